// Round 1
// baseline (297.606 us; speedup 1.0000x reference)
//
#include <hip/hip_runtime.h>
#include <hip/hip_bf16.h>
#include <stdint.h>

#define MM 100000   // rows in messages / idx
#define NN 200000   // rows in S / out
#define DD 128      // feature dim
#define BM 64       // message rows per block

typedef __attribute__((ext_vector_type(8))) short short8;
typedef __attribute__((ext_vector_type(4))) float f32x4;
typedef __attribute__((ext_vector_type(4))) unsigned short u16x4;

__device__ __forceinline__ unsigned short f2bf(float f) {
    union { float f; uint32_t u; } v; v.f = f;
    return (unsigned short)((v.u + 0x7FFFu + ((v.u >> 16) & 1u)) >> 16);  // RNE
}
__device__ __forceinline__ float bf2f(unsigned short s) {
    union { uint32_t u; float f; } v; v.u = ((uint32_t)s) << 16;
    return v.f;
}
__device__ __forceinline__ float sigmoidf(float x) {
    return 1.0f / (1.0f + __expf(-x));
}
__device__ __forceinline__ float tanh_fast(float x) {
    return 2.0f / (1.0f + __expf(-2.0f * x)) - 1.0f;
}

__global__ void fill_ones(f32x4* __restrict__ out, int n4) {
    int i = blockIdx.x * blockDim.x + threadIdx.x;
    int stride = gridDim.x * blockDim.x;
    f32x4 ones = {1.f, 1.f, 1.f, 1.f};
    for (; i < n4; i += stride) out[i] = ones;
}

__global__ void conv_w(const float* __restrict__ wih, const float* __restrict__ whh,
                       unsigned short* __restrict__ dst) {
    int i = blockIdx.x * blockDim.x + threadIdx.x;
    if (i < 3 * DD * DD) {
        dst[i] = f2bf(wih[i]);
        dst[3 * DD * DD + i] = f2bf(whh[i]);
    }
}

template <bool WBF16>
__device__ __forceinline__ short8 load_wfrag(const void* W, int row, int kbase) {
    if constexpr (WBF16) {
        const unsigned short* p = (const unsigned short*)W;
        return *reinterpret_cast<const short8*>(p + (size_t)row * DD + kbase);
    } else {
        const float* p = (const float*)W + (size_t)row * DD + kbase;
        f32x4 a = *reinterpret_cast<const f32x4*>(p);
        f32x4 b = *reinterpret_cast<const f32x4*>(p + 4);
        short8 r;
        r[0] = (short)f2bf(a[0]); r[1] = (short)f2bf(a[1]);
        r[2] = (short)f2bf(a[2]); r[3] = (short)f2bf(a[3]);
        r[4] = (short)f2bf(b[0]); r[5] = (short)f2bf(b[1]);
        r[6] = (short)f2bf(b[2]); r[7] = (short)f2bf(b[3]);
        return r;
    }
}

// 512 threads = 8 waves. Each wave owns 16 output columns (8*16=128).
// Block covers BM=64 message rows staged into LDS as bf16 (pitch 136 shorts
// = 272B: 272%32dw stride -> 2-way bank alias only, free per m136).
template <bool WBF16>
__global__ __launch_bounds__(512, 2) void gru_kernel(
    const float* __restrict__ msgs, const float* __restrict__ S,
    const void* __restrict__ Wih, const void* __restrict__ Whh,
    const float* __restrict__ b_ih, const float* __restrict__ b_hh,
    const int* __restrict__ idx, float* __restrict__ out)
{
    __shared__ unsigned short Xl[BM][136];
    __shared__ unsigned short Hl[BM][136];

    const int tid = threadIdx.x;
    const int mbase = blockIdx.x * BM;

    // ---- stage X (messages) and H (gathered S) as bf16 ----
    // 64 rows * 32 float4-chunks = 2048 tasks / 512 threads = 4 iters
    #pragma unroll
    for (int it = 0; it < 4; ++it) {
        int id = it * 512 + tid;
        int row = id >> 5, ch = id & 31;
        int m = mbase + row;
        f32x4 xv = {0.f, 0.f, 0.f, 0.f}, hv = {0.f, 0.f, 0.f, 0.f};
        if (m < MM) {
            xv = *reinterpret_cast<const f32x4*>(msgs + (size_t)m * DD + ch * 4);
            int si = idx[m];
            hv = *reinterpret_cast<const f32x4*>(S + (size_t)si * DD + ch * 4);
        }
        u16x4 xb, hb;
        #pragma unroll
        for (int j = 0; j < 4; ++j) { xb[j] = f2bf(xv[j]); hb[j] = f2bf(hv[j]); }
        *reinterpret_cast<u16x4*>(&Xl[row][ch * 4]) = xb;
        *reinterpret_cast<u16x4*>(&Hl[row][ch * 4]) = hb;
    }
    __syncthreads();

    const int wave = tid >> 6;
    const int lane = tid & 63;
    const int l15 = lane & 15;
    const int lk = lane >> 4;
    const int cbase = wave * 16;   // this wave's 16 output columns

    // acc[gate][mt] : C/D layout col=lane&15, row=(lane>>4)*4+reg  [m89]
    f32x4 accX[3][4], accH[3][4];
    #pragma unroll
    for (int g = 0; g < 3; ++g) {
        #pragma unroll
        for (int mt = 0; mt < 4; ++mt) {
            accX[g][mt] = (f32x4){0.f, 0.f, 0.f, 0.f};
            accH[g][mt] = (f32x4){0.f, 0.f, 0.f, 0.f};
        }
    }

    #pragma unroll
    for (int ks = 0; ks < 4; ++ks) {   // K = 128 in 4 steps of 32
        short8 ax[4], ah[4];
        #pragma unroll
        for (int mt = 0; mt < 4; ++mt) {
            ax[mt] = *reinterpret_cast<const short8*>(&Xl[mt * 16 + l15][ks * 32 + lk * 8]);
            ah[mt] = *reinterpret_cast<const short8*>(&Hl[mt * 16 + l15][ks * 32 + lk * 8]);
        }
        #pragma unroll
        for (int g = 0; g < 3; ++g) {
            int wrow = g * DD + cbase + l15;   // W row = output column
            int kb = ks * 32 + lk * 8;
            short8 bx = load_wfrag<WBF16>(Wih, wrow, kb);
            #pragma unroll
            for (int mt = 0; mt < 4; ++mt)
                accX[g][mt] = __builtin_amdgcn_mfma_f32_16x16x32_bf16(ax[mt], bx, accX[g][mt], 0, 0, 0);
            short8 bh = load_wfrag<WBF16>(Whh, wrow, kb);
            #pragma unroll
            for (int mt = 0; mt < 4; ++mt)
                accH[g][mt] = __builtin_amdgcn_mfma_f32_16x16x32_bf16(ah[mt], bh, accH[g][mt], 0, 0, 0);
        }
    }

    // ---- epilogue: gates + scatter ----
    const int c = cbase + l15;                       // 0..127
    float bir = b_ih[c], biz = b_ih[DD + c], bin_ = b_ih[2 * DD + c];
    float bhr = b_hh[c], bhz = b_hh[DD + c], bhn = b_hh[2 * DD + c];
    #pragma unroll
    for (int mt = 0; mt < 4; ++mt) {
        #pragma unroll
        for (int j = 0; j < 4; ++j) {
            int mloc = mt * 16 + lk * 4 + j;
            int m = mbase + mloc;
            if (m < MM) {
                float r = sigmoidf(accX[0][mt][j] + bir + accH[0][mt][j] + bhr);
                float z = sigmoidf(accX[1][mt][j] + biz + accH[1][mt][j] + bhz);
                float n = tanh_fast(accX[2][mt][j] + bin_ + r * (accH[2][mt][j] + bhn));
                float h = bf2f(Hl[mloc][c]);
                int o = idx[m];
                out[(size_t)o * DD + c] = (1.f - z) * n + z * h;
            }
        }
    }
}

extern "C" void kernel_launch(void* const* d_in, const int* in_sizes, int n_in,
                              void* d_out, int out_size, void* d_ws, size_t ws_size,
                              hipStream_t stream) {
    const float* msgs  = (const float*)d_in[0];
    const float* S     = (const float*)d_in[1];
    const float* W_ih  = (const float*)d_in[2];
    const float* W_hh  = (const float*)d_in[3];
    const float* b_ih  = (const float*)d_in[4];
    const float* b_hh  = (const float*)d_in[5];
    const int*   idx   = (const int*)d_in[6];
    float* out = (float*)d_out;

    // 1) initialize output to ones (GRU rows overwritten below, same stream)
    fill_ones<<<2048, 256, 0, stream>>>((f32x4*)out, NN * DD / 4);

    const int blocks = (MM + BM - 1) / BM;
    const size_t wbytes = (size_t)2 * 3 * DD * DD * sizeof(unsigned short);
    if (ws_size >= wbytes) {
        // 2) pre-convert weights to bf16 in workspace (halves per-block L2 traffic)
        unsigned short* wbf = (unsigned short*)d_ws;
        conv_w<<<(3 * DD * DD + 255) / 256, 256, 0, stream>>>(W_ih, W_hh, wbf);
        gru_kernel<true><<<blocks, 512, 0, stream>>>(msgs, S, wbf, wbf + 3 * DD * DD,
                                                     b_ih, b_hh, idx, out);
    } else {
        gru_kernel<false><<<blocks, 512, 0, stream>>>(msgs, S, W_ih, W_hh,
                                                      b_ih, b_hh, idx, out);
    }
}